// Round 2
// baseline (357.180 us; speedup 1.0000x reference)
//
#include <hip/hip_runtime.h>

namespace {

constexpr int kB = 16384;
constexpr int kC = 4;
constexpr int kH = 8;
constexpr int kT = 120;
constexpr float kAlpha  = 0.2f;
constexpr float kDT     = 10.0f;
constexpr float kThresh = 0.5f;
constexpr float kNever  = (float)kT * kDT;   // 1200.0f

__device__ __forceinline__ float fast_tanh(float x) {
    // tanh(x) = 1 - 2/(exp(2x)+1): v_exp_f32 + v_rcp_f32 path.
    float e = __expf(x + x);
    float r = __builtin_amdgcn_rcpf(e + 1.0f);
    return fmaf(-2.0f, r, 1.0f);
}

// Cross-lane xor within an aligned quad via DPP quad_perm (VALU, ~8 cyc,
// no LDS). xor1=[1,0,3,2]=0xB1, xor2=[2,3,0,1]=0x4E, xor3=[3,2,1,0]=0x1B.
template <int CTRL>
__device__ __forceinline__ float qperm(float x) {
    return __builtin_bit_cast(float, __builtin_amdgcn_mov_dpp(
        __builtin_bit_cast(int, x), CTRL, 0xF, 0xF, true));
}

__global__ __launch_bounds__(256) void acc_rnn_kernel(
    const float* __restrict__ logits,      // [B,C]
    const float* __restrict__ p_iscale,    // [1]
    const float* __restrict__ p_nstd,      // [1]
    const float* __restrict__ ipw_,        // [H,1]
    const float* __restrict__ ipb_,        // [H]
    const float* __restrict__ spw_,        // [H,H]
    const float* __restrict__ cpw_,        // [H,1]
    const float* __restrict__ evw_,        // [1,H]
    const float* __restrict__ evb_,        // [1]
    const float* __restrict__ cbias_,      // [C,H]
    const float* __restrict__ compmat_,    // [C,C]
    const float* __restrict__ noise_,      // [T,B,C,H]
    float* __restrict__ out)               // [B,C]
{
    const int tid = blockIdx.x * 256 + threadIdx.x;   // tid = b*C + c
    const int c   = tid & (kC - 1);

    const float iscale = p_iscale[0];
    const float nstd   = p_nstd[0];
    const float evb    = evb_[0];

    // Wave-uniform weights (uniform addresses -> scalarizable).
    float W[kH][kH], cpw[kH], evw[kH];
#pragma unroll
    for (int k = 0; k < kH; ++k) {
        cpw[k] = cpw_[k];
        evw[k] = evw_[k];
#pragma unroll
        for (int h = 0; h < kH; ++h) W[k][h] = spw_[k * kH + h];
    }

    // comp[c] = sum_{c'} ev[c'] * M[c', c]; e_j (quad xor j) carries weight M[c^j, c].
    const float mw0 = compmat_[(c ^ 0) * kC + c];
    const float mw1 = compmat_[(c ^ 1) * kC + c];
    const float mw2 = compmat_[(c ^ 2) * kC + c];
    const float mw3 = compmat_[(c ^ 3) * kC + c];

    // Time-constant input embedding.
    float rl = logits[tid] * iscale;
    rl = rl > 0.0f ? rl : 0.0f;
    float inp[kH];
#pragma unroll
    for (int k = 0; k < kH; ++k)
        inp[k] = fmaf(rl, ipw_[k], ipb_[k] + cbias_[c * kH + k]);

    float s[kH];
#pragma unroll
    for (int k = 0; k < kH; ++k) s[k] = 0.0f;
    float ev = evb;            // ev(state0); carried: new_ev(t) == ev used at t+1

    // Lane owns contiguous 32B: noise[t][b][c][0:8]  -> two float4 per step.
    const float4* np4 = (const float4*)noise_;
    const int stepStride = kB * kC * kH / 4;   // float4 per time step
    const int lane = tid * 2;

    // 6-deep prefetch ring: 12 float4 in flight per lane (48 KB/CU) -- well
    // past the BW*latency product at 1 wave/SIMD occupancy.
    float4 nb[6][2];
#pragma unroll
    for (int j = 0; j < 6; ++j) {
        nb[j][0] = np4[j * stepStride + lane];
        nb[j][1] = np4[j * stepStride + lane + 1];
    }

    float tdec = kNever;
    float tcf  = 0.0f;         // (t+1)*DT carried incrementally

    // One simulated step; PF: prefetch step t+6 into ring slot j.
    auto do_step = [&](int t, int j, bool PF) {
        // competition from carried evidence (tree-shaped, DPP cross-lane)
        float e1 = qperm<0xB1>(ev);
        float e2 = qperm<0x4E>(ev);
        float e3 = qperm<0x1B>(ev);
        float comp = fmaf(e1, mw1, ev * mw0) + fmaf(e3, mw3, e2 * mw2);

        float nz[kH] = {nb[j][0].x, nb[j][0].y, nb[j][0].z, nb[j][0].w,
                        nb[j][1].x, nb[j][1].y, nb[j][1].z, nb[j][1].w};

        if (PF) {
            nb[j][0] = np4[(t + 6) * stepStride + lane];
            nb[j][1] = np4[(t + 6) * stepStride + lane + 1];
        }

        float cand[kH];
#pragma unroll
        for (int k = 0; k < kH; ++k) {
            float a = fmaf(comp, cpw[k], inp[k]);
            a = fmaf(nz[k], nstd, a);
#pragma unroll
            for (int h = 0; h < kH; ++h) a = fmaf(s[h], W[k][h], a);
            cand[k] = fast_tanh(a);
        }

        float nev = evb;
#pragma unroll
        for (int k = 0; k < kH; ++k) {
            s[k] = fmaf(kAlpha, cand[k] - s[k], s[k]);
            nev = fmaf(s[k], evw[k], nev);
        }
        ev = nev;

        tcf += kDT;
        tdec = fminf(tdec, ev > kThresh ? tcf : kNever);
    };

    // Main: t0 = 0..108, prefetch always valid (t+6 <= 119).
    for (int t0 = 0; t0 < kT - 6; t0 += 6) {
#pragma unroll
        for (int j = 0; j < 6; ++j) do_step(t0 + j, j, true);
    }
    // Epilogue: t = 114..119, no prefetch.
#pragma unroll
    for (int j = 0; j < 6; ++j) do_step(kT - 6 + j, j, false);

    out[tid] = tdec * (1.0f / 1000.0f);
}

}  // namespace

extern "C" void kernel_launch(void* const* d_in, const int* in_sizes, int n_in,
                              void* d_out, int out_size, void* d_ws, size_t ws_size,
                              hipStream_t stream) {
    (void)in_sizes; (void)n_in; (void)d_ws; (void)ws_size; (void)out_size;
    const float* logits   = (const float*)d_in[0];
    const float* iscale   = (const float*)d_in[1];
    const float* nstd     = (const float*)d_in[2];
    const float* ipw      = (const float*)d_in[3];
    const float* ipb      = (const float*)d_in[4];
    const float* spw      = (const float*)d_in[5];
    const float* cpw      = (const float*)d_in[6];
    const float* evw      = (const float*)d_in[7];
    const float* evb      = (const float*)d_in[8];
    const float* cbias    = (const float*)d_in[9];
    const float* compmat  = (const float*)d_in[10];
    const float* noise    = (const float*)d_in[11];
    float* out = (float*)d_out;

    dim3 grid(kB * kC / 256), block(256);
    acc_rnn_kernel<<<grid, block, 0, stream>>>(
        logits, iscale, nstd, ipw, ipb, spw, cpw, evw, evb,
        cbias, compmat, noise, out);
}

// Round 3
// 347.895 us; speedup vs baseline: 1.0267x; 1.0267x over previous
//
#include <hip/hip_runtime.h>

namespace {

constexpr int kB = 16384;
constexpr int kC = 4;
constexpr int kH = 8;
constexpr int kT = 120;
constexpr float kAlpha  = 0.2f;
constexpr float kDT     = 10.0f;
constexpr float kThresh = 0.5f;
constexpr float kNever  = (float)kT * kDT;   // 1200.0f

typedef float vf4 __attribute__((ext_vector_type(4)));

__device__ __forceinline__ float fast_tanh(float x) {
    // tanh(x) = 1 - 2/(exp(2x)+1): v_exp_f32 + v_rcp_f32 path.
    float e = __expf(x + x);
    float r = __builtin_amdgcn_rcpf(e + 1.0f);
    return fmaf(-2.0f, r, 1.0f);
}

// DPP lane permutes (full-rate VALU, no LDS).
// quad_perm: xor1=[1,0,3,2]=0xB1, xor2=[2,3,0,1]=0x4E, xor3=[3,2,1,0]=0x1B.
// row_half_mirror (0x141): lane L gets L^7 within rows of 8.
template <int CTRL>
__device__ __forceinline__ float dppmov(float x) {
    return __builtin_bit_cast(float, __builtin_amdgcn_mov_dpp(
        __builtin_bit_cast(int, x), CTRL, 0xF, 0xF, true));
}
// value from lane^4: RHM (^7) then quad_perm[3,2,1,0] (^3) -> ^4.
__device__ __forceinline__ float xor4(float x) {
    return dppmov<0x1B>(dppmov<0x141>(x));
}

// Lane layout: tid = b*8 + half*4 + c.
//   - classes c=0..3 occupy aligned quads (both halves see all 4 classes)
//   - the h-half partner sits at lane^4 (same row of 8)
// Lane owns state rows k = half*4 .. half*4+3 and the matching 16B noise slice.
__global__ __launch_bounds__(256) void acc_rnn_kernel(
    const float* __restrict__ logits,      // [B,C]
    const float* __restrict__ p_iscale,    // [1]
    const float* __restrict__ p_nstd,      // [1]
    const float* __restrict__ ipw_,        // [H,1]
    const float* __restrict__ ipb_,        // [H]
    const float* __restrict__ spw_,        // [H,H]
    const float* __restrict__ cpw_,        // [H,1]
    const float* __restrict__ evw_,        // [1,H]
    const float* __restrict__ evb_,        // [1]
    const float* __restrict__ cbias_,      // [C,H]
    const float* __restrict__ compmat_,    // [C,C]
    const float* __restrict__ noise_,      // [T,B,C,H]
    float* __restrict__ out)               // [B,C]
{
    const int tid  = blockIdx.x * 256 + threadIdx.x;
    const int c    = tid & 3;
    const int half = (tid >> 2) & 1;
    const int kOfs = half << 2;            // own rows k = kOfs..kOfs+3
    const int pid  = ((tid >> 3) << 2) | c;   // b*4 + c

    const float iscale = p_iscale[0];
    const float nstd   = p_nstd[0];
    const float evb    = evb_[0];

    // Own-row weights; W columns pre-split into own-half / other-half so all
    // register arrays are compile-time-indexed (no scratch).
    float Wown[4][4], Woth[4][4], cpw[4], evw[4];
#pragma unroll
    for (int i = 0; i < 4; ++i) {
        const int k = kOfs + i;
        cpw[i] = cpw_[k];
        evw[i] = evw_[k];
#pragma unroll
        for (int j = 0; j < 4; ++j) {
            Wown[i][j] = spw_[k * kH + kOfs + j];
            Woth[i][j] = spw_[k * kH + (kOfs ^ 4) + j];
        }
    }

    // comp[c] = sum_{c'} ev[c'] * M[c', c]; quad-xor j partner carries M[c^j, c].
    const float mw0 = compmat_[(c ^ 0) * kC + c];
    const float mw1 = compmat_[(c ^ 1) * kC + c];
    const float mw2 = compmat_[(c ^ 2) * kC + c];
    const float mw3 = compmat_[(c ^ 3) * kC + c];

    // Time-constant input embedding for own rows.
    float rl = logits[pid] * iscale;
    rl = rl > 0.0f ? rl : 0.0f;
    float inp[4];
#pragma unroll
    for (int i = 0; i < 4; ++i)
        inp[i] = fmaf(rl, ipw_[kOfs + i], ipb_[kOfs + i] + cbias_[c * kH + kOfs + i]);

    float s[4] = {0.0f, 0.0f, 0.0f, 0.0f};
    float ev = evb;                        // ev(state0); carried across steps

    // Noise: lane owns the 16B slice noise[t][b][c][kOfs..kOfs+3].
    // float4 index = t*131072 + b*8 + c*2 + half  (contiguous 128B per 8 lanes).
    const vf4* np4 = (const vf4*)noise_;
    const int stepStride = kB * kC * kH / 4;   // 131072
    const int base = (tid & ~7) + ((tid & 3) << 1) + half;

    // 6-deep prefetch ring: 6 outstanding 16B loads/lane, 48 KB/CU in flight.
    vf4 nb[6];
#pragma unroll
    for (int j = 0; j < 6; ++j)
        nb[j] = __builtin_nontemporal_load(&np4[j * stepStride + base]);

    float tdec = kNever;
    float tcf  = 0.0f;

    auto do_step = [&](int t, int j, bool PF) {
        // competition from carried evidence (identical on both halves)
        float e1 = dppmov<0xB1>(ev);
        float e2 = dppmov<0x4E>(ev);
        float e3 = dppmov<0x1B>(ev);
        float comp = fmaf(e1, mw1, ev * mw0) + fmaf(e3, mw3, e2 * mw2);

        float nz[4] = {nb[j].x, nb[j].y, nb[j].z, nb[j].w};
        if (PF)
            nb[j] = __builtin_nontemporal_load(&np4[(t + 6) * stepStride + base]);

        // partner's 4 state rows via lane^4 DPP
        float so[4];
#pragma unroll
        for (int i = 0; i < 4; ++i) so[i] = xor4(s[i]);

        float cand[4];
#pragma unroll
        for (int i = 0; i < 4; ++i) {
            float a = fmaf(comp, cpw[i], inp[i]);
            a = fmaf(nz[i], nstd, a);
#pragma unroll
            for (int j2 = 0; j2 < 4; ++j2) a = fmaf(s[j2],  Wown[i][j2], a);
#pragma unroll
            for (int j2 = 0; j2 < 4; ++j2) a = fmaf(so[j2], Woth[i][j2], a);
            cand[i] = fast_tanh(a);
        }

        float evp = 0.0f;
#pragma unroll
        for (int i = 0; i < 4; ++i) {
            s[i] = fmaf(kAlpha, cand[i] - s[i], s[i]);
            evp = fmaf(s[i], evw[i], evp);
        }
        ev = (evp + xor4(evp)) + evb;      // full evidence, identical on both halves

        tcf += kDT;
        tdec = fminf(tdec, ev > kThresh ? tcf : kNever);
    };

    // Main: prefetch always valid (t+6 <= 119 for t <= 113).
    for (int t0 = 0; t0 < kT - 6; t0 += 6) {
#pragma unroll
        for (int j = 0; j < 6; ++j) do_step(t0 + j, j, true);
    }
    // Epilogue: t = 114..119, no prefetch.
#pragma unroll
    for (int j = 0; j < 6; ++j) do_step(kT - 6 + j, j, false);

    if (half == 0) out[pid] = tdec * (1.0f / 1000.0f);
}

}  // namespace

extern "C" void kernel_launch(void* const* d_in, const int* in_sizes, int n_in,
                              void* d_out, int out_size, void* d_ws, size_t ws_size,
                              hipStream_t stream) {
    (void)in_sizes; (void)n_in; (void)d_ws; (void)ws_size; (void)out_size;
    const float* logits   = (const float*)d_in[0];
    const float* iscale   = (const float*)d_in[1];
    const float* nstd     = (const float*)d_in[2];
    const float* ipw      = (const float*)d_in[3];
    const float* ipb      = (const float*)d_in[4];
    const float* spw      = (const float*)d_in[5];
    const float* cpw      = (const float*)d_in[6];
    const float* evw      = (const float*)d_in[7];
    const float* evb      = (const float*)d_in[8];
    const float* cbias    = (const float*)d_in[9];
    const float* compmat  = (const float*)d_in[10];
    const float* noise    = (const float*)d_in[11];
    float* out = (float*)d_out;

    // 2 lanes per (b,c): 131072 threads.
    dim3 grid(kB * kC * 2 / 256), block(256);
    acc_rnn_kernel<<<grid, block, 0, stream>>>(
        logits, iscale, nstd, ipw, ipb, spw, cpw, evw, evb,
        cbias, compmat, noise, out);
}